// Round 1
// baseline (5635.905 us; speedup 1.0000x reference)
//
#include <hip/hip_runtime.h>
#include <math.h>

namespace {

constexpr int BN = 16;      // batch
constexpr int CN = 64;      // input channels
constexpr int HN = 128;     // hidden
constexpr int GN = 64;      // grid dim (G1 == G2)
constexpr int KH = 2 * HN;          // 256  (Hcat width)
constexpr int KTOT = KH + CN;       // 320  (Hcat + x fused K)
constexpr int KCH = 32;             // K-chunk staged in LDS
constexpr int NCH = KTOT / KCH;     // 10 chunks

__device__ __forceinline__ float sigmoidf_(float z) {
    return 1.f / (1.f + expf(-z));
}

// One block = one (cell, slice). slice -> (dim dd, hidden half h0).
// Block computes gate rows {q*128 + h0 + h : q in 0..3, h in 0..63} for dim dd,
// i.e. all 4 gates for 64 hidden units, for all 16 batches.
__global__ __launch_bounds__(256, 1) void diag_kernel(
    const float* __restrict__ x,      // [B, C, G, G]
    const float* __restrict__ Wih,    // [2, 512, 64]
    const float* __restrict__ Whh,    // [2, 512, 256]
    const float* __restrict__ bih,    // [2, 512]
    const float* __restrict__ bhh,    // [2, 512]
    float* __restrict__ out,          // [B, 256, G, G]  (h1: ch 0..127, h2: ch 128..255)
    float* __restrict__ cbuf,         // ws: c1[G(j)][B][H] then c2[G(i)][B][H]
    int d)                            // anti-diagonal index, i + j == d
{
    __shared__ float Hc[BN][KTOT];        // 16 x 320 fp32 = 20 KB
    __shared__ float Wch[KCH][257];       // 32 x 257 fp32 = 32.9 KB (padded)

    const int cell  = blockIdx.x >> 2;
    const int slice = blockIdx.x & 3;
    const int dd = slice >> 1;            // grid-LSTM dim 0/1
    const int h0 = (slice & 1) * 64;      // hidden-unit half
    const int i0 = (d > GN - 1) ? (d - (GN - 1)) : 0;
    const int i = i0 + cell;
    const int j = d - i;
    const int t = threadIdx.x;

    // ---- stage Hcat = [h1(i-1,j) | h2(i,j-1) | x(:,:,i,j)] ----
    for (int e = t; e < BN * KTOT; e += 256) {
        const int b = e / KTOT;
        const int k = e - b * KTOT;
        float v;
        if (k < HN) {
            v = (i > 0) ? out[((b * 2 * HN + k) * GN + (i - 1)) * GN + j] : 0.f;
        } else if (k < KH) {
            v = (j > 0) ? out[((b * 2 * HN + k) * GN + i) * GN + (j - 1)] : 0.f;
        } else {
            v = x[((b * CN + (k - KH)) * GN + i) * GN + j];
        }
        Hc[b][k] = v;
    }

    const int h  = t & 63;    // hidden unit within the 64-slice (compute role)
    const int bg = t >> 6;    // batch group: b in {bg*4 .. bg*4+3}   (compute role)
    // staging role: thread t stages gate row q*128 + h0 + h with q = t>>6
    const int grow = dd * 4 * HN + bg * HN + h0 + h;   // global gate row for staging

    float acc[4][4];
    #pragma unroll
    for (int qq = 0; qq < 4; ++qq)
        #pragma unroll
        for (int bb = 0; bb < 4; ++bb) acc[qq][bb] = 0.f;

    for (int kb = 0; kb < NCH; ++kb) {
        const int kbase = kb * KCH;
        __syncthreads();   // Hcat ready (kb==0) / previous chunk consumed
        // stage W chunk transposed: Wch[kk][q*64 + h]  (column index == t)
        {
            const float* src = (kbase < KH) ? (Whh + (size_t)grow * KH + kbase)
                                            : (Wih + (size_t)grow * CN + (kbase - KH));
            #pragma unroll
            for (int k4 = 0; k4 < KCH / 4; ++k4) {
                const float4 w = *(const float4*)(src + k4 * 4);
                Wch[k4 * 4 + 0][t] = w.x;
                Wch[k4 * 4 + 1][t] = w.y;
                Wch[k4 * 4 + 2][t] = w.z;
                Wch[k4 * 4 + 3][t] = w.w;
            }
        }
        __syncthreads();
        #pragma unroll 8
        for (int kk = 0; kk < KCH; ++kk) {
            const float w0 = Wch[kk][0 * 64 + h];
            const float w1 = Wch[kk][1 * 64 + h];
            const float w2 = Wch[kk][2 * 64 + h];
            const float w3 = Wch[kk][3 * 64 + h];
            #pragma unroll
            for (int bb = 0; bb < 4; ++bb) {
                const float hv = Hc[bg * 4 + bb][kbase + kk];   // wave-uniform broadcast
                acc[0][bb] = fmaf(w0, hv, acc[0][bb]);
                acc[1][bb] = fmaf(w1, hv, acc[1][bb]);
                acc[2][bb] = fmaf(w2, hv, acc[2][bb]);
                acc[3][bb] = fmaf(w3, hv, acc[3][bb]);
            }
        }
    }

    // ---- bias + LSTM nonlinearity + state update ----
    const int hu = h0 + h;
    float bias[4];
    #pragma unroll
    for (int qq = 0; qq < 4; ++qq) {
        const int gidx = dd * 4 * HN + qq * HN + hu;
        bias[qq] = bih[gidx] + bhh[gidx];
    }
    // dim-0 cell state flows down rows -> indexed by column j;
    // dim-1 cell state flows along a row -> indexed by row i.
    float* cptr = (dd == 0) ? (cbuf + (size_t)j * BN * HN)
                            : (cbuf + (size_t)GN * BN * HN + (size_t)i * BN * HN);
    const bool has_prev = (dd == 0) ? (i > 0) : (j > 0);

    #pragma unroll
    for (int bb = 0; bb < 4; ++bb) {
        const int b = bg * 4 + bb;
        const float gi = sigmoidf_(acc[0][bb] + bias[0]);
        const float gf = sigmoidf_(acc[1][bb] + bias[1]);
        const float gg = tanhf(acc[2][bb] + bias[2]);
        const float go = sigmoidf_(acc[3][bb] + bias[3]);
        const float cp = has_prev ? cptr[b * HN + hu] : 0.f;
        const float c  = gf * cp + gi * gg;
        cptr[b * HN + hu] = c;
        out[((b * 2 * HN + dd * HN + hu) * GN + i) * GN + j] = go * tanhf(c);
    }
}

} // anonymous namespace

extern "C" void kernel_launch(void* const* d_in, const int* in_sizes, int n_in,
                              void* d_out, int out_size, void* d_ws, size_t ws_size,
                              hipStream_t stream) {
    const float* x   = (const float*)d_in[0];
    const float* Wih = (const float*)d_in[1];
    const float* Whh = (const float*)d_in[2];
    const float* bih = (const float*)d_in[3];
    const float* bhh = (const float*)d_in[4];
    float* out  = (float*)d_out;
    float* cbuf = (float*)d_ws;   // needs 2*64*16*128*4 B = 1 MB

    // Wavefront over anti-diagonals: cells on diagonal d are independent.
    for (int d = 0; d < 2 * GN - 1; ++d) {
        const int i0 = (d > GN - 1) ? (d - (GN - 1)) : 0;
        const int i1 = (d < GN - 1) ? d : (GN - 1);
        const int nc = i1 - i0 + 1;
        hipLaunchKernelGGL(diag_kernel, dim3(nc * 4), dim3(256), 0, stream,
                           x, Wih, Whh, bih, bhh, out, cbuf, d);
    }
}